// Round 8
// baseline (5581.659 us; speedup 1.0000x reference)
//
// pendulumRNNSA — persistent 2-layer LSTM (B=256,T=512,H=256) + fused MFMA attention.
//
// Round 8 — round 7's tag-in-data exchange with the init hole fixed:
//  * Each h element is a u64: upper 32 = phase tag, lower 32 = (hi|lo) bf16
//    pair. ONE relaxed agent-scope 8B store publishes data+tag atomically;
//    consumers poll the data words directly, retrying stale elements only.
//    One L3 round trip per phase (round 6 had three: store->drain->flag->poll).
//  * ROUND-7 BUG FIXED: init must cover exactly the states never produced
//    in-loop: Hb1[par0]=(tag0,0), Hb2[par0]=(tag0,0), Hb2[par1]=(tag1,0).
//    (Hb2 tag-1 is read at phase 1 but phase 0's cell-2 branch never writes —
//    all threads spun to guard expiry on poison, ~tens of ms/launch -> harness
//    timeout. Hb1[par1] must NOT be pre-tagged: phase 0 writes real tag-1 there.)
//  * Race-free: entering phase k requires having READ all tag-k words, which
//    producers wrote only after their phase-(k-1) reads of the buffer being
//    overwritten (data dependence through the cell compute orders store after
//    load). Max producer-consumer skew = 2 phases = buffer depth.
//  * Bounded retry (2^14 rounds, s_sleep after 64) -> degrades, never hangs.
#include <hip/hip_runtime.h>
#include <hip/hip_bf16.h>

#define HD   256
#define TT   512

typedef unsigned short u16;
typedef unsigned int   u32;
typedef unsigned long long u64;
typedef __attribute__((ext_vector_type(8))) short  short8;
typedef __attribute__((ext_vector_type(4))) float  f32x4;

__device__ __forceinline__ float bf2f(u16 v) { return __uint_as_float(((u32)v) << 16); }
__device__ __forceinline__ u16 f2bf(float f) {
    u32 u = __float_as_uint(f);
    u32 r = u + 0x7fffu + ((u >> 16) & 1u);   // RNE
    return (u16)(r >> 16);
}
__device__ __forceinline__ float sigf(float x)  { return __builtin_amdgcn_rcpf(1.f + __expf(-x)); }
__device__ __forceinline__ float tanhf_(float x){ float e = __expf(-2.f * x);
                                                  return 2.f * __builtin_amdgcn_rcpf(1.f + e) - 1.f; }

__global__ void cvt_bf_kernel(const float* __restrict__ src, u16* __restrict__ dst, int n) {
    int idx = blockIdx.x * 256 + threadIdx.x;
    if (idx < n) dst[idx] = f2bf(src[idx]);
}

__global__ void bias_kernel(const float* __restrict__ a1, const float* __restrict__ b1,
                            const float* __restrict__ a2, const float* __restrict__ b2,
                            float* __restrict__ o1, float* __restrict__ o2) {
    int i = blockIdx.x * 256 + threadIdx.x;
    o1[i] = a1[i] + b1[i];
    o2[i] = a2[i] + b2[i];
}

__device__ __forceinline__ void load_bfrag(const float* __restrict__ W, int row, int kq, short8* bw) {
#pragma unroll
    for (int kk = 0; kk < 8; ++kk) {
        const float* p = W + row * 256 + kk * 32 + kq * 8;
        short8 s;
#pragma unroll
        for (int j = 0; j < 8; ++j) s[j] = (short)f2bf(p[j]);
        bw[kk] = s;
    }
}

__device__ __forceinline__ u64 aload(const u64* p) {
    return __hip_atomic_load(p, __ATOMIC_RELAXED, __HIP_MEMORY_SCOPE_AGENT);
}
__device__ __forceinline__ void astore(u64* p, u64 v) {
    __hip_atomic_store(p, v, __ATOMIC_RELAXED, __HIP_MEMORY_SCOPE_AGENT);
}

// Hb layout: [parity][256 batch][256 hidden] u64 = (tag << 32) | (hi bf16) | (lo bf16 << 16).
__global__ __launch_bounds__(256, 1) void lstm_persist(
    const float* __restrict__ x,
    const float* __restrict__ Wih1,
    const float* __restrict__ bias1,
    const float* __restrict__ bias2,
    const float* __restrict__ Whh1,
    const float* __restrict__ Wih2,
    const float* __restrict__ Whh2,
    u64* __restrict__ Hb1, u64* __restrict__ Hb2,
    u16* __restrict__ H2out)
{
    __shared__ __align__(16) u16 sh1hi[16 * 264], sh1lo[16 * 264];
    __shared__ __align__(16) u16 sh2hi[16 * 264], sh2lo[16 * 264];
    __shared__ float xs[TT * 16];
    __shared__ float gbuf1[4 * 16 * 18], gbuf2[4 * 16 * 18];
    __shared__ float wihs[64], b1s[64], b2s[64];

    const int tid = threadIdx.x;
    const int blk = blockIdx.x, gb = blk >> 4, hg = blk & 15;
    const int l = tid & 63, wv = tid >> 6;
    const int nloc = l & 15, kq = l >> 4;
    const int wrow = wv * 256 + hg * 16 + nloc;

    short8 bW1[8], bW2[8], bW3[8];
    load_bfrag(Whh1, wrow, kq, bW1);
    load_bfrag(Wih2, wrow, kq, bW2);
    load_bfrag(Whh2, wrow, kq, bW3);

    for (int idx = tid; idx < 16 * TT; idx += 256) {
        int b = idx >> 9, t = idx & 511;
        xs[t * 16 + b] = x[(gb * 16 + b) * TT + t];
    }
    if (tid < 64) {
        int rr = (tid >> 4) * 256 + hg * 16 + (tid & 15);
        wihs[tid] = Wih1[rr]; b1s[tid] = bias1[rr]; b2s[tid] = bias2[rr];
    }

    // init: publish exactly the states never produced in-loop (own patch):
    //   Hb1[par0] = (tag 0, h1(-1)=0)   read at k=0
    //   Hb2[par0] = (tag 0, h2(-2)=0)   read at k=0
    //   Hb2[par1] = (tag 1, h2(-1)=0)   read at k=1  <-- round-7's missing piece
    // Hb1[par1] is NOT pre-tagged: phase 0 writes the real tag-1 value there.
    const int cb = tid >> 4, ci = tid & 15;
    const int bg = gb * 16 + cb, ig = hg * 16 + ci;
    astore(&Hb1[((0 * 256 + bg) << 8) + ig], 0ull);
    astore(&Hb2[((0 * 256 + bg) << 8) + ig], 0ull);
    astore(&Hb2[((1 * 256 + bg) << 8) + ig], 1ull << 32);
    float c1 = 0.f, c2 = 0.f;

    const int aoff = nloc * 264 + kq * 8;
    const int sb = tid >> 4, scol = (tid & 15) * 16;   // staging: row sb, cols scol..scol+15
    const int sbase = sb * 264 + scol;

    for (int k = 0; k <= TT; ++k) {
        const int rp = k & 1, wp = rp ^ 1;
        const u32 want = (u32)k;

        // ---- stage h1(k-1), h2(k-2): 16 tagged u64 per buffer per thread,
        //      retry stale elements until the tag matches.
        {
            const u64* p1 = Hb1 + ((rp * 256 + gb * 16 + sb) << 8) + scol;
            const u64* p2 = Hb2 + ((rp * 256 + gb * 16 + sb) << 8) + scol;
            u64 v1[16], v2[16];
#pragma unroll
            for (int j = 0; j < 16; ++j) v1[j] = aload(p1 + j);
#pragma unroll
            for (int j = 0; j < 16; ++j) v2[j] = aload(p2 + j);
            int guard = 0;
            while (true) {
                u32 st1 = 0, st2 = 0;
#pragma unroll
                for (int j = 0; j < 16; ++j) st1 |= ((u32)(v1[j] >> 32) != want) ? (1u << j) : 0u;
#pragma unroll
                for (int j = 0; j < 16; ++j) st2 |= ((u32)(v2[j] >> 32) != want) ? (1u << j) : 0u;
                if (!(st1 | st2) || ++guard > (1 << 14)) break;
                if (guard > 64) __builtin_amdgcn_s_sleep(1);
#pragma unroll
                for (int j = 0; j < 16; ++j) if (st1 & (1u << j)) v1[j] = aload(p1 + j);
#pragma unroll
                for (int j = 0; j < 16; ++j) if (st2 & (1u << j)) v2[j] = aload(p2 + j);
            }
            // unpack hi|lo planes, vectorized LDS stores (b128 x2 per plane)
            u32 h1h[8], h1l[8], h2h[8], h2l[8];
#pragma unroll
            for (int i = 0; i < 8; ++i) {
                u32 a = (u32)v1[2 * i], b = (u32)v1[2 * i + 1];
                h1h[i] = (a & 0xffffu) | (b << 16);
                h1l[i] = (a >> 16) | (b & 0xffff0000u);
                a = (u32)v2[2 * i]; b = (u32)v2[2 * i + 1];
                h2h[i] = (a & 0xffffu) | (b << 16);
                h2l[i] = (a >> 16) | (b & 0xffff0000u);
            }
            *(uint4*)(sh1hi + sbase) = *(uint4*)(h1h);     *(uint4*)(sh1hi + sbase + 8) = *(uint4*)(h1h + 4);
            *(uint4*)(sh1lo + sbase) = *(uint4*)(h1l);     *(uint4*)(sh1lo + sbase + 8) = *(uint4*)(h1l + 4);
            *(uint4*)(sh2hi + sbase) = *(uint4*)(h2h);     *(uint4*)(sh2hi + sbase + 8) = *(uint4*)(h2h + 4);
            *(uint4*)(sh2lo + sbase) = *(uint4*)(h2l);     *(uint4*)(sh2lo + sbase + 8) = *(uint4*)(h2l + 4);
        }
        __syncthreads();

        f32x4 acc1a = {0,0,0,0}, acc1b = {0,0,0,0};
        f32x4 acc2a = {0,0,0,0}, acc2b = {0,0,0,0};
#pragma unroll
        for (int kk = 0; kk < 8; ++kk) {
            short8 a1h = *(const short8*)(sh1hi + aoff + kk * 32);
            short8 a1l = *(const short8*)(sh1lo + aoff + kk * 32);
            if (k < TT) {
                acc1a = __builtin_amdgcn_mfma_f32_16x16x32_bf16(a1h, bW1[kk], acc1a, 0, 0, 0);
                acc1b = __builtin_amdgcn_mfma_f32_16x16x32_bf16(a1l, bW1[kk], acc1b, 0, 0, 0);
            }
            if (k > 0) {
                acc2a = __builtin_amdgcn_mfma_f32_16x16x32_bf16(a1h, bW2[kk], acc2a, 0, 0, 0);
                acc2b = __builtin_amdgcn_mfma_f32_16x16x32_bf16(a1l, bW2[kk], acc2b, 0, 0, 0);
                short8 a2h = *(const short8*)(sh2hi + aoff + kk * 32);
                short8 a2l = *(const short8*)(sh2lo + aoff + kk * 32);
                acc2a = __builtin_amdgcn_mfma_f32_16x16x32_bf16(a2h, bW3[kk], acc2a, 0, 0, 0);
                acc2b = __builtin_amdgcn_mfma_f32_16x16x32_bf16(a2l, bW3[kk], acc2b, 0, 0, 0);
            }
        }
        // D layout: col(n)=lane&15, row(m)=(lane>>4)*4+reg
#pragma unroll
        for (int r = 0; r < 4; ++r) {
            int m = (l >> 4) * 4 + r;
            gbuf1[(wv * 16 + m) * 18 + nloc] = acc1a[r] + acc1b[r];
            gbuf2[(wv * 16 + m) * 18 + nloc] = acc2a[r] + acc2b[r];
        }
        __syncthreads();

        u16 hi2 = 0;
        if (k < TT) {   // cell 1, t = k -> publish h1(k) with tag k+1
            float xv = xs[k * 16 + cb];
            float g0 = gbuf1[(0 * 16 + cb) * 18 + ci] + xv * wihs[ci]      + b1s[ci];
            float g1 = gbuf1[(1 * 16 + cb) * 18 + ci] + xv * wihs[16 + ci] + b1s[16 + ci];
            float g2 = gbuf1[(2 * 16 + cb) * 18 + ci] + xv * wihs[32 + ci] + b1s[32 + ci];
            float g3 = gbuf1[(3 * 16 + cb) * 18 + ci] + xv * wihs[48 + ci] + b1s[48 + ci];
            float ii = sigf(g0), ff = sigf(g1), gg = tanhf_(g2), oo = sigf(g3);
            c1 = ff * c1 + ii * gg;
            float h = oo * tanhf_(c1);
            u16 hi = f2bf(h);
            u32 pack = (u32)hi | ((u32)f2bf(h - bf2f(hi)) << 16);
            astore(&Hb1[((wp * 256 + bg) << 8) + ig], ((u64)(u32)(k + 1) << 32) | (u64)pack);
        }
        if (k > 0) {    // cell 2, t = k-1 -> publish h2(k-1) with tag k+1
            float g0 = gbuf2[(0 * 16 + cb) * 18 + ci] + b2s[ci];
            float g1 = gbuf2[(1 * 16 + cb) * 18 + ci] + b2s[16 + ci];
            float g2 = gbuf2[(2 * 16 + cb) * 18 + ci] + b2s[32 + ci];
            float g3 = gbuf2[(3 * 16 + cb) * 18 + ci] + b2s[48 + ci];
            float ii = sigf(g0), ff = sigf(g1), gg = tanhf_(g2), oo = sigf(g3);
            c2 = ff * c2 + ii * gg;
            float h = oo * tanhf_(c2);
            hi2 = f2bf(h);
            if (k < TT) {   // store at k==TT never read
                u32 pack = (u32)hi2 | ((u32)f2bf(h - bf2f(hi2)) << 16);
                astore(&Hb2[((wp * 256 + bg) << 8) + ig], ((u64)(u32)(k + 1) << 32) | (u64)pack);
            }
            // HBM store for the attention pass — off the inter-block critical path
            H2out[(bg * TT + (k - 1)) * 256 + ig] = hi2;
        }
    }
}

// ---- fused attention: per 64-row tile, S1=tanh(H2@Wa1^T+ba1) -> S2=S1@Wa2^T+ba2
//      -> softmax rows -> out = sum_n p*h2*Wo + bo. MFMA for both matmuls.
__global__ __launch_bounds__(256) void attn_fused(
    const u16*  __restrict__ Wa1b, const u16* __restrict__ Wa2b,
    const float* __restrict__ ba1, const float* __restrict__ ba2,
    const float* __restrict__ Wo,  const float* __restrict__ bo,
    const u16*  __restrict__ H2,   float* __restrict__ out)
{
    __shared__ __align__(16) u16 sA[64 * 264];
    __shared__ __align__(16) u16 sP[64 * 264];
    __shared__ float red[64 * 12];
    __shared__ float sb1[256], sb2[256], swo[256];

    const int tid = threadIdx.x;
    const int w = tid >> 6, l = tid & 63;
    const int c = l & 15, q = l >> 4;
    const int row0 = blockIdx.x * 64;

    {
        const int r = tid >> 2, qq = tid & 3;
        const uint4* src = (const uint4*)(H2 + (row0 + r) * 256 + qq * 64);
#pragma unroll
        for (int j = 0; j < 8; ++j) {
            uint4 v = src[j];
            *(uint4*)(sA + r * 264 + qq * 64 + j * 8) = v;
        }
    }
    if (tid < 256) { sb1[tid] = ba1[tid]; sb2[tid] = ba2[tid]; swo[tid] = Wo[tid]; }
    __syncthreads();

    f32x4 acc[4][4];
#pragma unroll
    for (int mi = 0; mi < 4; ++mi)
#pragma unroll
        for (int ni = 0; ni < 4; ++ni) acc[mi][ni] = (f32x4){0,0,0,0};

#pragma unroll
    for (int ni = 0; ni < 4; ++ni) {
        const int row = w * 64 + ni * 16 + c;
        const u16* wp = Wa1b + row * 256 + q * 8;
        short8 bW[8];
#pragma unroll
        for (int kk = 0; kk < 8; ++kk) bW[kk] = *(const short8*)(wp + kk * 32);
#pragma unroll
        for (int kk = 0; kk < 8; ++kk)
#pragma unroll
            for (int mi = 0; mi < 4; ++mi) {
                short8 a = *(const short8*)(sA + (mi * 16 + c) * 264 + q * 8 + kk * 32);
                acc[mi][ni] = __builtin_amdgcn_mfma_f32_16x16x32_bf16(a, bW[kk], acc[mi][ni], 0, 0, 0);
            }
    }
#pragma unroll
    for (int mi = 0; mi < 4; ++mi)
#pragma unroll
        for (int ni = 0; ni < 4; ++ni) {
            const int n = w * 64 + ni * 16 + c;
            const float bj = sb1[n];
#pragma unroll
            for (int r = 0; r < 4; ++r) {
                int m = mi * 16 + q * 4 + r;
                sP[m * 264 + n] = f2bf(tanhf(acc[mi][ni][r] + bj));
            }
        }
    __syncthreads();

#pragma unroll
    for (int mi = 0; mi < 4; ++mi)
#pragma unroll
        for (int ni = 0; ni < 4; ++ni) acc[mi][ni] = (f32x4){0,0,0,0};
#pragma unroll
    for (int ni = 0; ni < 4; ++ni) {
        const int row = w * 64 + ni * 16 + c;
        const u16* wp = Wa2b + row * 256 + q * 8;
        short8 bW[8];
#pragma unroll
        for (int kk = 0; kk < 8; ++kk) bW[kk] = *(const short8*)(wp + kk * 32);
#pragma unroll
        for (int kk = 0; kk < 8; ++kk)
#pragma unroll
            for (int mi = 0; mi < 4; ++mi) {
                short8 a = *(const short8*)(sP + (mi * 16 + c) * 264 + q * 8 + kk * 32);
                acc[mi][ni] = __builtin_amdgcn_mfma_f32_16x16x32_bf16(a, bW[kk], acc[mi][ni], 0, 0, 0);
            }
    }

    float mx[4][4];
#pragma unroll
    for (int mi = 0; mi < 4; ++mi)
#pragma unroll
        for (int r = 0; r < 4; ++r) mx[mi][r] = -1e30f;
#pragma unroll
    for (int mi = 0; mi < 4; ++mi)
#pragma unroll
        for (int ni = 0; ni < 4; ++ni) {
            const float bj = sb2[w * 64 + ni * 16 + c];
#pragma unroll
            for (int r = 0; r < 4; ++r) {
                float s = acc[mi][ni][r] + bj;
                acc[mi][ni][r] = s;
                mx[mi][r] = fmaxf(mx[mi][r], s);
            }
        }
#pragma unroll
    for (int off = 1; off < 16; off <<= 1)
#pragma unroll
        for (int mi = 0; mi < 4; ++mi)
#pragma unroll
            for (int r = 0; r < 4; ++r) mx[mi][r] = fmaxf(mx[mi][r], __shfl_xor(mx[mi][r], off));
    if (c == 0)
#pragma unroll
        for (int mi = 0; mi < 4; ++mi)
#pragma unroll
            for (int r = 0; r < 4; ++r) red[(mi * 16 + q * 4 + r) * 12 + w] = mx[mi][r];
    __syncthreads();
#pragma unroll
    for (int mi = 0; mi < 4; ++mi)
#pragma unroll
        for (int r = 0; r < 4; ++r) {
            const float* rp = red + (mi * 16 + q * 4 + r) * 12;
            mx[mi][r] = fmaxf(fmaxf(rp[0], rp[1]), fmaxf(rp[2], rp[3]));
        }
    float suml[4][4], sumw[4][4];
#pragma unroll
    for (int mi = 0; mi < 4; ++mi)
#pragma unroll
        for (int r = 0; r < 4; ++r) { suml[mi][r] = 0.f; sumw[mi][r] = 0.f; }
#pragma unroll
    for (int mi = 0; mi < 4; ++mi)
#pragma unroll
        for (int ni = 0; ni < 4; ++ni) {
            const int n = w * 64 + ni * 16 + c;
            const float wov = swo[n];
#pragma unroll
            for (int r = 0; r < 4; ++r) {
                int m = mi * 16 + q * 4 + r;
                float e = __expf(acc[mi][ni][r] - mx[mi][r]);
                suml[mi][r] += e;
                sumw[mi][r] += e * bf2f(sA[m * 264 + n]) * wov;
            }
        }
#pragma unroll
    for (int off = 1; off < 16; off <<= 1)
#pragma unroll
        for (int mi = 0; mi < 4; ++mi)
#pragma unroll
            for (int r = 0; r < 4; ++r) {
                suml[mi][r] += __shfl_xor(suml[mi][r], off);
                sumw[mi][r] += __shfl_xor(sumw[mi][r], off);
            }
    __syncthreads();
    if (c == 0)
#pragma unroll
        for (int mi = 0; mi < 4; ++mi)
#pragma unroll
            for (int r = 0; r < 4; ++r) {
                int m = mi * 16 + q * 4 + r;
                red[m * 12 + 4 + w] = suml[mi][r];
                red[m * 12 + 8 + w] = sumw[mi][r];
            }
    __syncthreads();
    if (tid < 64) {
        const float* rp = red + tid * 12;
        float lsum = rp[4] + rp[5] + rp[6] + rp[7];
        float wsum = rp[8] + rp[9] + rp[10] + rp[11];
        out[row0 + tid] = wsum / lsum + bo[0];
    }
}

extern "C" void kernel_launch(void* const* d_in, const int* in_sizes, int n_in,
                              void* d_out, int out_size, void* d_ws, size_t ws_size,
                              hipStream_t stream) {
    const float* x    = (const float*)d_in[0];
    const float* Wih1 = (const float*)d_in[1];
    const float* bih1 = (const float*)d_in[2];
    const float* Whh1 = (const float*)d_in[3];
    const float* bhh1 = (const float*)d_in[4];
    const float* Wih2 = (const float*)d_in[5];
    const float* bih2 = (const float*)d_in[6];
    const float* Whh2 = (const float*)d_in[7];
    const float* bhh2 = (const float*)d_in[8];
    const float* Wa1  = (const float*)d_in[9];
    const float* ba1  = (const float*)d_in[10];
    const float* Wa2  = (const float*)d_in[11];
    const float* ba2  = (const float*)d_in[12];
    const float* Wo   = (const float*)d_in[13];
    const float* bo   = (const float*)d_in[14];

    char* ws = (char*)d_ws;
    u16*   Wa1b  = (u16*)(ws + 0);                  // 128 KB
    u16*   Wa2b  = (u16*)(ws + 131072);             // 128 KB
    float* bias1 = (float*)(ws + 262144);           // 4 KB
    float* bias2 = (float*)(ws + 266240);           // 4 KB
    u64*   Hb1   = (u64*)(ws + 1048576);            // 1 MB [2][256][256] u64
    u64*   Hb2   = (u64*)(ws + 2097152);            // 1 MB
    u16*   H2    = (u16*)(ws + 4194304);            // 64 MB
    float* out   = (float*)d_out;

    bias_kernel<<<4, 256, 0, stream>>>(bih1, bhh1, bih2, bhh2, bias1, bias2);
    cvt_bf_kernel<<<256, 256, 0, stream>>>(Wa1, Wa1b, 65536);
    cvt_bf_kernel<<<256, 256, 0, stream>>>(Wa2, Wa2b, 65536);

    lstm_persist<<<256, 256, 0, stream>>>(x, Wih1, bias1, bias2,
                                          Whh1, Wih2, Whh2, Hb1, Hb2, H2);
    attn_fused<<<2048, 256, 0, stream>>>(Wa1b, Wa2b, ba1, ba2, Wo, bo, H2, out);
}

// Round 9
// 5554.144 us; speedup vs baseline: 1.0050x; 1.0050x over previous
//
// pendulumRNNSA — persistent 2-layer LSTM (B=256,T=512,H=256) + fused MFMA attention.
//
// Round 9 — tag-in-data kept; poll bandwidth fixed; layer-split critical path:
//  * Exchange word: u64 = (tag<<32) | hi bf16 | lo bf16<<16. One relaxed
//    agent-scope 8B store publishes data+tag atomically (1 hop/phase).
//  * ROUND-8 FIX: each thread's 16 staging words come from ONE producer block
//    (hidden-group = tid&15) -> poll a single representative word (512 KB/round
//    grid-wide vs round 8's 16 MB/round which saturated L3/HBM and doubled
//    FETCH_SIZE), then bulk-load + tag-verify individually (rare retries).
//  * Phase split in two sub-stages: [poll h1 -> MFMA1 -> cell1 -> publish h1(k)]
//    then [poll h2 -> MFMA2 (reuses sh1) -> cell2 -> publish h2(k-1) + H2out].
//    The recurrence-critical loop is h1-only; h2 has ~a full phase of slack.
//    Overwrite safety: consuming X's h1(k-1)/h2(k-2) proves X already read the
//    parity buffer we overwrite (program order in X) — per-stage induction.
//  * Init (round-8 fix retained): Hb1[par0]=(tag0,0), Hb2[par0]=(tag0,0),
//    Hb2[par1]=(tag1,0); Hb1[par1] NOT pre-tagged (phase 0 writes real tag-1).
//  * All spins bounded -> degrades to wrong answer, never hangs.
#include <hip/hip_runtime.h>
#include <hip/hip_bf16.h>

#define HD   256
#define TT   512

typedef unsigned short u16;
typedef unsigned int   u32;
typedef unsigned long long u64;
typedef __attribute__((ext_vector_type(8))) short  short8;
typedef __attribute__((ext_vector_type(4))) float  f32x4;

__device__ __forceinline__ float bf2f(u16 v) { return __uint_as_float(((u32)v) << 16); }
__device__ __forceinline__ u16 f2bf(float f) {
    u32 u = __float_as_uint(f);
    u32 r = u + 0x7fffu + ((u >> 16) & 1u);   // RNE
    return (u16)(r >> 16);
}
__device__ __forceinline__ float sigf(float x)  { return __builtin_amdgcn_rcpf(1.f + __expf(-x)); }
__device__ __forceinline__ float tanhf_(float x){ float e = __expf(-2.f * x);
                                                  return 2.f * __builtin_amdgcn_rcpf(1.f + e) - 1.f; }

__global__ void cvt_bf_kernel(const float* __restrict__ src, u16* __restrict__ dst, int n) {
    int idx = blockIdx.x * 256 + threadIdx.x;
    if (idx < n) dst[idx] = f2bf(src[idx]);
}

__global__ void bias_kernel(const float* __restrict__ a1, const float* __restrict__ b1,
                            const float* __restrict__ a2, const float* __restrict__ b2,
                            float* __restrict__ o1, float* __restrict__ o2) {
    int i = blockIdx.x * 256 + threadIdx.x;
    o1[i] = a1[i] + b1[i];
    o2[i] = a2[i] + b2[i];
}

__device__ __forceinline__ void load_bfrag(const float* __restrict__ W, int row, int kq, short8* bw) {
#pragma unroll
    for (int kk = 0; kk < 8; ++kk) {
        const float* p = W + row * 256 + kk * 32 + kq * 8;
        short8 s;
#pragma unroll
        for (int j = 0; j < 8; ++j) s[j] = (short)f2bf(p[j]);
        bw[kk] = s;
    }
}

__device__ __forceinline__ u64 aload(const u64* p) {
    return __hip_atomic_load(p, __ATOMIC_RELAXED, __HIP_MEMORY_SCOPE_AGENT);
}
__device__ __forceinline__ void astore(u64* p, u64 v) {
    __hip_atomic_store(p, v, __ATOMIC_RELAXED, __HIP_MEMORY_SCOPE_AGENT);
}

// poll word 0 (all 16 words share one producer block), then bulk-load + verify.
__device__ __forceinline__ void fetch16(const u64* p, u32 want, u64* v) {
    int g = 0;
    u64 t = aload(p);
    while ((u32)(t >> 32) != want) {
        if (++g > (1 << 16)) break;
        if (g > 4) __builtin_amdgcn_s_sleep(1);
        t = aload(p);
    }
    v[0] = t;
#pragma unroll
    for (int j = 1; j < 16; ++j) v[j] = aload(p + j);
    g = 0;
    while (true) {
        u32 st = 0;
#pragma unroll
        for (int j = 1; j < 16; ++j) st |= ((u32)(v[j] >> 32) != want) ? (1u << j) : 0u;
        if (!st || ++g > (1 << 16)) break;
#pragma unroll
        for (int j = 1; j < 16; ++j) if (st & (1u << j)) v[j] = aload(p + j);
    }
}

// unpack 16 tagged words into hi/lo planes and store to LDS (2x b128 each)
__device__ __forceinline__ void unpack16(const u64* v, u16* shhi, u16* shlo, int sbase) {
    u32 hh[8], hl[8];
#pragma unroll
    for (int i = 0; i < 8; ++i) {
        u32 a = (u32)v[2 * i], b = (u32)v[2 * i + 1];
        hh[i] = (a & 0xffffu) | (b << 16);
        hl[i] = (a >> 16) | (b & 0xffff0000u);
    }
    *(uint4*)(shhi + sbase) = *(uint4*)(hh);   *(uint4*)(shhi + sbase + 8) = *(uint4*)(hh + 4);
    *(uint4*)(shlo + sbase) = *(uint4*)(hl);   *(uint4*)(shlo + sbase + 8) = *(uint4*)(hl + 4);
}

// Hb layout: [parity][256 batch][256 hidden] u64.
__global__ __launch_bounds__(256, 1) void lstm_persist(
    const float* __restrict__ x,
    const float* __restrict__ Wih1,
    const float* __restrict__ bias1,
    const float* __restrict__ bias2,
    const float* __restrict__ Whh1,
    const float* __restrict__ Wih2,
    const float* __restrict__ Whh2,
    u64* __restrict__ Hb1, u64* __restrict__ Hb2,
    u16* __restrict__ H2out)
{
    __shared__ __align__(16) u16 sh1hi[16 * 264], sh1lo[16 * 264];
    __shared__ __align__(16) u16 sh2hi[16 * 264], sh2lo[16 * 264];
    __shared__ float xs[TT * 16];
    __shared__ float gbuf1[4 * 16 * 18], gbuf2[4 * 16 * 18];
    __shared__ float wihs[64], b1s[64], b2s[64];

    const int tid = threadIdx.x;
    const int blk = blockIdx.x, gb = blk >> 4, hg = blk & 15;
    const int l = tid & 63, wv = tid >> 6;
    const int nloc = l & 15, kq = l >> 4;
    const int wrow = wv * 256 + hg * 16 + nloc;

    short8 bW1[8], bW2[8], bW3[8];
    load_bfrag(Whh1, wrow, kq, bW1);
    load_bfrag(Wih2, wrow, kq, bW2);
    load_bfrag(Whh2, wrow, kq, bW3);

    for (int idx = tid; idx < 16 * TT; idx += 256) {
        int b = idx >> 9, t = idx & 511;
        xs[t * 16 + b] = x[(gb * 16 + b) * TT + t];
    }
    if (tid < 64) {
        int rr = (tid >> 4) * 256 + hg * 16 + (tid & 15);
        wihs[tid] = Wih1[rr]; b1s[tid] = bias1[rr]; b2s[tid] = bias2[rr];
    }

    // init: exactly the states never produced in-loop (own patch)
    const int cb = tid >> 4, ci = tid & 15;
    const int bg = gb * 16 + cb, ig = hg * 16 + ci;
    astore(&Hb1[((0 * 256 + bg) << 8) + ig], 0ull);
    astore(&Hb2[((0 * 256 + bg) << 8) + ig], 0ull);
    astore(&Hb2[((1 * 256 + bg) << 8) + ig], 1ull << 32);
    float c1 = 0.f, c2 = 0.f;

    const int aoff = nloc * 264 + kq * 8;
    const int sb = tid >> 4, scol = (tid & 15) * 16;   // staging: row sb, cols scol..+15 (ONE producer: hg'=tid&15)
    const int sbase = sb * 264 + scol;

    for (int k = 0; k <= TT; ++k) {
        const int rp = k & 1, wp = rp ^ 1;
        const u32 want = (u32)k;

        // ================= stage 1: h1 =================
        {
            u64 v1[16];
            fetch16(Hb1 + ((rp * 256 + gb * 16 + sb) << 8) + scol, want, v1);
            unpack16(v1, sh1hi, sh1lo, sbase);
        }
        __syncthreads();

        f32x4 acc1a = {0,0,0,0}, acc1b = {0,0,0,0};
        if (k < TT) {
#pragma unroll
            for (int kk = 0; kk < 8; ++kk) {
                short8 a1h = *(const short8*)(sh1hi + aoff + kk * 32);
                short8 a1l = *(const short8*)(sh1lo + aoff + kk * 32);
                acc1a = __builtin_amdgcn_mfma_f32_16x16x32_bf16(a1h, bW1[kk], acc1a, 0, 0, 0);
                acc1b = __builtin_amdgcn_mfma_f32_16x16x32_bf16(a1l, bW1[kk], acc1b, 0, 0, 0);
            }
        }
#pragma unroll
        for (int r = 0; r < 4; ++r) {
            int m = (l >> 4) * 4 + r;
            gbuf1[(wv * 16 + m) * 18 + nloc] = acc1a[r] + acc1b[r];
        }
        __syncthreads();

        if (k < TT) {   // cell 1, t = k -> publish h1(k) tagged k+1 (EARLY)
            float xv = xs[k * 16 + cb];
            float g0 = gbuf1[(0 * 16 + cb) * 18 + ci] + xv * wihs[ci]      + b1s[ci];
            float g1 = gbuf1[(1 * 16 + cb) * 18 + ci] + xv * wihs[16 + ci] + b1s[16 + ci];
            float g2 = gbuf1[(2 * 16 + cb) * 18 + ci] + xv * wihs[32 + ci] + b1s[32 + ci];
            float g3 = gbuf1[(3 * 16 + cb) * 18 + ci] + xv * wihs[48 + ci] + b1s[48 + ci];
            float ii = sigf(g0), ff = sigf(g1), gg = tanhf_(g2), oo = sigf(g3);
            c1 = ff * c1 + ii * gg;
            float h = oo * tanhf_(c1);
            u16 hi = f2bf(h);
            u32 pack = (u32)hi | ((u32)f2bf(h - bf2f(hi)) << 16);
            astore(&Hb1[((wp * 256 + bg) << 8) + ig], ((u64)(u32)(k + 1) << 32) | (u64)pack);
        }

        // ================= stage 2: h2 =================
        {
            u64 v2[16];
            fetch16(Hb2 + ((rp * 256 + gb * 16 + sb) << 8) + scol, want, v2);
            unpack16(v2, sh2hi, sh2lo, sbase);
        }
        __syncthreads();

        f32x4 acc2a = {0,0,0,0}, acc2b = {0,0,0,0};
        if (k > 0) {
#pragma unroll
            for (int kk = 0; kk < 8; ++kk) {
                short8 a1h = *(const short8*)(sh1hi + aoff + kk * 32);   // sh1 still valid
                short8 a1l = *(const short8*)(sh1lo + aoff + kk * 32);
                acc2a = __builtin_amdgcn_mfma_f32_16x16x32_bf16(a1h, bW2[kk], acc2a, 0, 0, 0);
                acc2b = __builtin_amdgcn_mfma_f32_16x16x32_bf16(a1l, bW2[kk], acc2b, 0, 0, 0);
                short8 a2h = *(const short8*)(sh2hi + aoff + kk * 32);
                short8 a2l = *(const short8*)(sh2lo + aoff + kk * 32);
                acc2a = __builtin_amdgcn_mfma_f32_16x16x32_bf16(a2h, bW3[kk], acc2a, 0, 0, 0);
                acc2b = __builtin_amdgcn_mfma_f32_16x16x32_bf16(a2l, bW3[kk], acc2b, 0, 0, 0);
            }
        }
#pragma unroll
        for (int r = 0; r < 4; ++r) {
            int m = (l >> 4) * 4 + r;
            gbuf2[(wv * 16 + m) * 18 + nloc] = acc2a[r] + acc2b[r];
        }
        __syncthreads();

        if (k > 0) {    // cell 2, t = k-1 -> publish h2(k-1) tagged k+1
            float g0 = gbuf2[(0 * 16 + cb) * 18 + ci] + b2s[ci];
            float g1 = gbuf2[(1 * 16 + cb) * 18 + ci] + b2s[16 + ci];
            float g2 = gbuf2[(2 * 16 + cb) * 18 + ci] + b2s[32 + ci];
            float g3 = gbuf2[(3 * 16 + cb) * 18 + ci] + b2s[48 + ci];
            float ii = sigf(g0), ff = sigf(g1), gg = tanhf_(g2), oo = sigf(g3);
            c2 = ff * c2 + ii * gg;
            float h = oo * tanhf_(c2);
            u16 hi2 = f2bf(h);
            if (k < TT) {
                u32 pack = (u32)hi2 | ((u32)f2bf(h - bf2f(hi2)) << 16);
                astore(&Hb2[((wp * 256 + bg) << 8) + ig], ((u64)(u32)(k + 1) << 32) | (u64)pack);
            }
            H2out[(bg * TT + (k - 1)) * 256 + ig] = hi2;   // HBM, off critical path
        }
    }
}

// ---- fused attention: per 64-row tile, S1=tanh(H2@Wa1^T+ba1) -> S2=S1@Wa2^T+ba2
//      -> softmax rows -> out = sum_n p*h2*Wo + bo. MFMA for both matmuls.
__global__ __launch_bounds__(256) void attn_fused(
    const u16*  __restrict__ Wa1b, const u16* __restrict__ Wa2b,
    const float* __restrict__ ba1, const float* __restrict__ ba2,
    const float* __restrict__ Wo,  const float* __restrict__ bo,
    const u16*  __restrict__ H2,   float* __restrict__ out)
{
    __shared__ __align__(16) u16 sA[64 * 264];
    __shared__ __align__(16) u16 sP[64 * 264];
    __shared__ float red[64 * 12];
    __shared__ float sb1[256], sb2[256], swo[256];

    const int tid = threadIdx.x;
    const int w = tid >> 6, l = tid & 63;
    const int c = l & 15, q = l >> 4;
    const int row0 = blockIdx.x * 64;

    {
        const int r = tid >> 2, qq = tid & 3;
        const uint4* src = (const uint4*)(H2 + (row0 + r) * 256 + qq * 64);
#pragma unroll
        for (int j = 0; j < 8; ++j) {
            uint4 v = src[j];
            *(uint4*)(sA + r * 264 + qq * 64 + j * 8) = v;
        }
    }
    if (tid < 256) { sb1[tid] = ba1[tid]; sb2[tid] = ba2[tid]; swo[tid] = Wo[tid]; }
    __syncthreads();

    f32x4 acc[4][4];
#pragma unroll
    for (int mi = 0; mi < 4; ++mi)
#pragma unroll
        for (int ni = 0; ni < 4; ++ni) acc[mi][ni] = (f32x4){0,0,0,0};

#pragma unroll
    for (int ni = 0; ni < 4; ++ni) {
        const int row = w * 64 + ni * 16 + c;
        const u16* wp = Wa1b + row * 256 + q * 8;
        short8 bW[8];
#pragma unroll
        for (int kk = 0; kk < 8; ++kk) bW[kk] = *(const short8*)(wp + kk * 32);
#pragma unroll
        for (int kk = 0; kk < 8; ++kk)
#pragma unroll
            for (int mi = 0; mi < 4; ++mi) {
                short8 a = *(const short8*)(sA + (mi * 16 + c) * 264 + q * 8 + kk * 32);
                acc[mi][ni] = __builtin_amdgcn_mfma_f32_16x16x32_bf16(a, bW[kk], acc[mi][ni], 0, 0, 0);
            }
    }
#pragma unroll
    for (int mi = 0; mi < 4; ++mi)
#pragma unroll
        for (int ni = 0; ni < 4; ++ni) {
            const int n = w * 64 + ni * 16 + c;
            const float bj = sb1[n];
#pragma unroll
            for (int r = 0; r < 4; ++r) {
                int m = mi * 16 + q * 4 + r;
                sP[m * 264 + n] = f2bf(tanhf(acc[mi][ni][r] + bj));
            }
        }
    __syncthreads();

#pragma unroll
    for (int mi = 0; mi < 4; ++mi)
#pragma unroll
        for (int ni = 0; ni < 4; ++ni) acc[mi][ni] = (f32x4){0,0,0,0};
#pragma unroll
    for (int ni = 0; ni < 4; ++ni) {
        const int row = w * 64 + ni * 16 + c;
        const u16* wp = Wa2b + row * 256 + q * 8;
        short8 bW[8];
#pragma unroll
        for (int kk = 0; kk < 8; ++kk) bW[kk] = *(const short8*)(wp + kk * 32);
#pragma unroll
        for (int kk = 0; kk < 8; ++kk)
#pragma unroll
            for (int mi = 0; mi < 4; ++mi) {
                short8 a = *(const short8*)(sP + (mi * 16 + c) * 264 + q * 8 + kk * 32);
                acc[mi][ni] = __builtin_amdgcn_mfma_f32_16x16x32_bf16(a, bW[kk], acc[mi][ni], 0, 0, 0);
            }
    }

    float mx[4][4];
#pragma unroll
    for (int mi = 0; mi < 4; ++mi)
#pragma unroll
        for (int r = 0; r < 4; ++r) mx[mi][r] = -1e30f;
#pragma unroll
    for (int mi = 0; mi < 4; ++mi)
#pragma unroll
        for (int ni = 0; ni < 4; ++ni) {
            const float bj = sb2[w * 64 + ni * 16 + c];
#pragma unroll
            for (int r = 0; r < 4; ++r) {
                float s = acc[mi][ni][r] + bj;
                acc[mi][ni][r] = s;
                mx[mi][r] = fmaxf(mx[mi][r], s);
            }
        }
#pragma unroll
    for (int off = 1; off < 16; off <<= 1)
#pragma unroll
        for (int mi = 0; mi < 4; ++mi)
#pragma unroll
            for (int r = 0; r < 4; ++r) mx[mi][r] = fmaxf(mx[mi][r], __shfl_xor(mx[mi][r], off));
    if (c == 0)
#pragma unroll
        for (int mi = 0; mi < 4; ++mi)
#pragma unroll
            for (int r = 0; r < 4; ++r) red[(mi * 16 + q * 4 + r) * 12 + w] = mx[mi][r];
    __syncthreads();
#pragma unroll
    for (int mi = 0; mi < 4; ++mi)
#pragma unroll
        for (int r = 0; r < 4; ++r) {
            const float* rp = red + (mi * 16 + q * 4 + r) * 12;
            mx[mi][r] = fmaxf(fmaxf(rp[0], rp[1]), fmaxf(rp[2], rp[3]));
        }
    float suml[4][4], sumw[4][4];
#pragma unroll
    for (int mi = 0; mi < 4; ++mi)
#pragma unroll
        for (int r = 0; r < 4; ++r) { suml[mi][r] = 0.f; sumw[mi][r] = 0.f; }
#pragma unroll
    for (int mi = 0; mi < 4; ++mi)
#pragma unroll
        for (int ni = 0; ni < 4; ++ni) {
            const int n = w * 64 + ni * 16 + c;
            const float wov = swo[n];
#pragma unroll
            for (int r = 0; r < 4; ++r) {
                int m = mi * 16 + q * 4 + r;
                float e = __expf(acc[mi][ni][r] - mx[mi][r]);
                suml[mi][r] += e;
                sumw[mi][r] += e * bf2f(sA[m * 264 + n]) * wov;
            }
        }
#pragma unroll
    for (int off = 1; off < 16; off <<= 1)
#pragma unroll
        for (int mi = 0; mi < 4; ++mi)
#pragma unroll
            for (int r = 0; r < 4; ++r) {
                suml[mi][r] += __shfl_xor(suml[mi][r], off);
                sumw[mi][r] += __shfl_xor(sumw[mi][r], off);
            }
    __syncthreads();
    if (c == 0)
#pragma unroll
        for (int mi = 0; mi < 4; ++mi)
#pragma unroll
            for (int r = 0; r < 4; ++r) {
                int m = mi * 16 + q * 4 + r;
                red[m * 12 + 4 + w] = suml[mi][r];
                red[m * 12 + 8 + w] = sumw[mi][r];
            }
    __syncthreads();
    if (tid < 64) {
        const float* rp = red + tid * 12;
        float lsum = rp[4] + rp[5] + rp[6] + rp[7];
        float wsum = rp[8] + rp[9] + rp[10] + rp[11];
        out[row0 + tid] = wsum / lsum + bo[0];
    }
}

extern "C" void kernel_launch(void* const* d_in, const int* in_sizes, int n_in,
                              void* d_out, int out_size, void* d_ws, size_t ws_size,
                              hipStream_t stream) {
    const float* x    = (const float*)d_in[0];
    const float* Wih1 = (const float*)d_in[1];
    const float* bih1 = (const float*)d_in[2];
    const float* Whh1 = (const float*)d_in[3];
    const float* bhh1 = (const float*)d_in[4];
    const float* Wih2 = (const float*)d_in[5];
    const float* bih2 = (const float*)d_in[6];
    const float* Whh2 = (const float*)d_in[7];
    const float* bhh2 = (const float*)d_in[8];
    const float* Wa1  = (const float*)d_in[9];
    const float* ba1  = (const float*)d_in[10];
    const float* Wa2  = (const float*)d_in[11];
    const float* ba2  = (const float*)d_in[12];
    const float* Wo   = (const float*)d_in[13];
    const float* bo   = (const float*)d_in[14];

    char* ws = (char*)d_ws;
    u16*   Wa1b  = (u16*)(ws + 0);                  // 128 KB
    u16*   Wa2b  = (u16*)(ws + 131072);             // 128 KB
    float* bias1 = (float*)(ws + 262144);           // 4 KB
    float* bias2 = (float*)(ws + 266240);           // 4 KB
    u64*   Hb1   = (u64*)(ws + 1048576);            // 1 MB [2][256][256] u64
    u64*   Hb2   = (u64*)(ws + 2097152);            // 1 MB
    u16*   H2    = (u16*)(ws + 4194304);            // 64 MB
    float* out   = (float*)d_out;

    bias_kernel<<<4, 256, 0, stream>>>(bih1, bhh1, bih2, bhh2, bias1, bias2);
    cvt_bf_kernel<<<256, 256, 0, stream>>>(Wa1, Wa1b, 65536);
    cvt_bf_kernel<<<256, 256, 0, stream>>>(Wa2, Wa2b, 65536);

    lstm_persist<<<256, 256, 0, stream>>>(x, Wih1, bias1, bias2,
                                          Whh1, Wih2, Whh2, Hb1, Hb2, H2);
    attn_fused<<<2048, 256, 0, stream>>>(Wa1b, Wa2b, ba1, ba2, Wo, bo, H2, out);
}

// Round 10
// 2218.492 us; speedup vs baseline: 2.5160x; 2.5036x over previous
//
// pendulumRNNSA — persistent 2-layer LSTM (B=256,T=512,H=256) + fused MFMA attention.
//
// Round 10 — round-6 protocol, HALVED exchange demand:
//  * Quantitative model from rounds 6/8/9: phase time ≈ HBM-missed exchange
//    bytes (~26% of demand) at ~470 GB/s effective. Demand = consumers × data.
//  * Change ONE variable: 128 blocks x 512 threads (16 batch-groups x 8
//    hidden-groups) instead of 256x256 (16x16). Consumers per produced h
//    element: 16 -> 8 => read demand 8 -> 4 MB/phase. Straggler population
//    halves. Per-thread weight VGPRs unchanged (96).
//  * Everything else = round 6 verbatim: u32 (hi|lo bf16) exchange @ relaxed
//    agent scope (~fp23 recurrence), per-group flag barrier (8 private slots),
//    bounded spins (degrade, never hang), H2out stored after flag post.
//  * 1 state/thread cell update (512 = 16 batch x 32 hidden). LDS ~86 KB ->
//    1 block/CU; 128 blocks on 256 CUs: co-residency guaranteed.
#include <hip/hip_runtime.h>
#include <hip/hip_bf16.h>

#define HD   256
#define TT   512

typedef unsigned short u16;
typedef unsigned int   u32;
typedef unsigned long long u64;
typedef __attribute__((ext_vector_type(8))) short  short8;
typedef __attribute__((ext_vector_type(4))) float  f32x4;

__device__ __forceinline__ float bf2f(u16 v) { return __uint_as_float(((u32)v) << 16); }
__device__ __forceinline__ u16 f2bf(float f) {
    u32 u = __float_as_uint(f);
    u32 r = u + 0x7fffu + ((u >> 16) & 1u);   // RNE
    return (u16)(r >> 16);
}
__device__ __forceinline__ float sigf(float x)  { return __builtin_amdgcn_rcpf(1.f + __expf(-x)); }
__device__ __forceinline__ float tanhf_(float x){ float e = __expf(-2.f * x);
                                                  return 2.f * __builtin_amdgcn_rcpf(1.f + e) - 1.f; }

__global__ void cvt_bf_kernel(const float* __restrict__ src, u16* __restrict__ dst, int n) {
    int idx = blockIdx.x * 256 + threadIdx.x;
    if (idx < n) dst[idx] = f2bf(src[idx]);
}

__global__ void bias_kernel(const float* __restrict__ a1, const float* __restrict__ b1,
                            const float* __restrict__ a2, const float* __restrict__ b2,
                            float* __restrict__ o1, float* __restrict__ o2) {
    int i = blockIdx.x * 256 + threadIdx.x;
    o1[i] = a1[i] + b1[i];
    o2[i] = a2[i] + b2[i];
}

__device__ __forceinline__ void load_bfrag(const float* __restrict__ W, int row, int kq, short8* bw) {
#pragma unroll
    for (int kk = 0; kk < 8; ++kk) {
        const float* p = W + row * 256 + kk * 32 + kq * 8;
        short8 s;
#pragma unroll
        for (int j = 0; j < 8; ++j) s[j] = (short)f2bf(p[j]);
        bw[kk] = s;
    }
}

__device__ __forceinline__ u64 aload64(const u64* p) {
    return __hip_atomic_load(p, __ATOMIC_RELAXED, __HIP_MEMORY_SCOPE_AGENT);
}
__device__ __forceinline__ void astore32(u32* p, u32 v) {
    __hip_atomic_store(p, v, __ATOMIC_RELAXED, __HIP_MEMORY_SCOPE_AGENT);
}

// flag wait: lanes 0..7 poll the group's 8 slots (relaxed agent loads).
__device__ __forceinline__ void flag_wait(const u32* flags, int gb, u32 target) {
    if (threadIdx.x < 8) {
        const u32* slot = flags + (gb * 8 + (int)threadIdx.x) * 32;
        int sp = 0;
        while (__hip_atomic_load(slot, __ATOMIC_RELAXED, __HIP_MEMORY_SCOPE_AGENT) < target) {
            if (++sp > (1 << 24)) break;
        }
    }
    __syncthreads();
}

// flag post: __syncthreads drains vmcnt(0) (h stores at the coherent point),
// then leader publishes the phase to this block's private slot.
__device__ __forceinline__ void flag_post(u32* flags, int slotidx, u32 val) {
    __syncthreads();
    if (threadIdx.x == 0)
        __hip_atomic_store(flags + slotidx * 32, val, __ATOMIC_RELAXED, __HIP_MEMORY_SCOPE_AGENT);
}

// Hb layout: [parity][256 batch][256 hidden] u32 = (hi bf16) | (lo bf16 << 16).
__global__ __launch_bounds__(512) void lstm_persist(
    const float* __restrict__ x,
    const float* __restrict__ Wih1,
    const float* __restrict__ bias1,
    const float* __restrict__ bias2,
    const float* __restrict__ Whh1,
    const float* __restrict__ Wih2,
    const float* __restrict__ Whh2,
    u32* __restrict__ Hb1, u32* __restrict__ Hb2,
    u16* __restrict__ H2out, u32* flags)
{
    __shared__ __align__(16) u16 sh1hi[16 * 264], sh1lo[16 * 264];
    __shared__ __align__(16) u16 sh2hi[16 * 264], sh2lo[16 * 264];
    __shared__ float xs[TT * 16];
    __shared__ float gbuf1[4 * 16 * 36], gbuf2[4 * 16 * 36];
    __shared__ float wihs[128], b1s[128], b2s[128];

    const int tid = threadIdx.x;
    const int blk = blockIdx.x;              // 0..127
    const int gb = blk >> 3, hg = blk & 7;   // 16 batch-groups x 8 hidden-groups
    const int l = tid & 63, wv = tid >> 6;   // 8 waves
    const int g = wv >> 1, hh = wv & 1;      // gate, hidden-half
    const int nloc = l & 15, kq = l >> 4;
    const int wrow = g * 256 + hg * 32 + hh * 16 + nloc;   // this lane's gate row

    short8 bW1[8], bW2[8], bW3[8];
    load_bfrag(Whh1, wrow, kq, bW1);
    load_bfrag(Wih2, wrow, kq, bW2);
    load_bfrag(Whh2, wrow, kq, bW3);

    for (int idx = tid; idx < 16 * TT; idx += 512) {
        int b = idx >> 9, t = idx & 511;
        xs[t * 16 + b] = x[(gb * 16 + b) * TT + t];
    }
    if (tid < 128) {
        int rr = (tid >> 5) * 256 + hg * 32 + (tid & 31);   // gate=tid>>5, local=tid&31
        wihs[tid] = Wih1[rr]; b1s[tid] = bias1[rr]; b2s[tid] = bias2[rr];
    }

    // zero own state patches (both parities) — ws is re-poisoned each launch
    const int cb = tid >> 5, ci = tid & 31;                 // 16 batch x 32 hidden = 512
    const int bg = gb * 16 + cb, ig = hg * 32 + ci;
#pragma unroll
    for (int pp = 0; pp < 2; ++pp) {
        astore32(&Hb1[((pp * 256 + bg) << 8) + ig], 0u);
        astore32(&Hb2[((pp * 256 + bg) << 8) + ig], 0u);
    }
    float c1 = 0.f, c2 = 0.f;

    flag_post(flags, gb * 8 + hg, 1u);   // phase-1: zeroing done

    const int aoff = nloc * 264 + kq * 8;
    const int sb = tid >> 5, scol = (tid & 31) * 8;   // staging: row sb, cols scol..scol+7
    const int sbase = sb * 264 + scol;

    for (int k = 0; k <= TT; ++k) {
        flag_wait(flags, gb, (u32)(k + 1));

        const int rp = k & 1, wp = rp ^ 1;
        // ---- stage h1(k-1), h2(k-2): 8 u32 from each buffer per thread (4x 8B loads)
        {
            const u32* p1 = Hb1 + ((rp * 256 + gb * 16 + sb) << 8) + scol;
            const u32* p2 = Hb2 + ((rp * 256 + gb * 16 + sb) << 8) + scol;
            u32 w1v[8], w2v[8];
#pragma unroll
            for (int j = 0; j < 4; ++j) {
                u64 t = aload64((const u64*)p1 + j);
                w1v[2 * j] = (u32)t; w1v[2 * j + 1] = (u32)(t >> 32);
            }
#pragma unroll
            for (int j = 0; j < 4; ++j) {
                u64 t = aload64((const u64*)p2 + j);
                w2v[2 * j] = (u32)t; w2v[2 * j + 1] = (u32)(t >> 32);
            }
            // unpack hi|lo planes -> one b128 LDS store per plane
            u32 h1h[4], h1l[4], h2h[4], h2l[4];
#pragma unroll
            for (int i = 0; i < 4; ++i) {
                u32 a = w1v[2 * i], b = w1v[2 * i + 1];
                h1h[i] = (a & 0xffffu) | (b << 16);
                h1l[i] = (a >> 16) | (b & 0xffff0000u);
                a = w2v[2 * i]; b = w2v[2 * i + 1];
                h2h[i] = (a & 0xffffu) | (b << 16);
                h2l[i] = (a >> 16) | (b & 0xffff0000u);
            }
            *(uint4*)(sh1hi + sbase) = *(uint4*)(h1h);
            *(uint4*)(sh1lo + sbase) = *(uint4*)(h1l);
            *(uint4*)(sh2hi + sbase) = *(uint4*)(h2h);
            *(uint4*)(sh2lo + sbase) = *(uint4*)(h2l);
        }
        __syncthreads();

        f32x4 acc1a = {0,0,0,0}, acc1b = {0,0,0,0};
        f32x4 acc2a = {0,0,0,0}, acc2b = {0,0,0,0};
#pragma unroll
        for (int kk = 0; kk < 8; ++kk) {
            short8 a1h = *(const short8*)(sh1hi + aoff + kk * 32);
            short8 a1l = *(const short8*)(sh1lo + aoff + kk * 32);
            if (k < TT) {
                acc1a = __builtin_amdgcn_mfma_f32_16x16x32_bf16(a1h, bW1[kk], acc1a, 0, 0, 0);
                acc1b = __builtin_amdgcn_mfma_f32_16x16x32_bf16(a1l, bW1[kk], acc1b, 0, 0, 0);
            }
            if (k > 0) {
                acc2a = __builtin_amdgcn_mfma_f32_16x16x32_bf16(a1h, bW2[kk], acc2a, 0, 0, 0);
                acc2b = __builtin_amdgcn_mfma_f32_16x16x32_bf16(a1l, bW2[kk], acc2b, 0, 0, 0);
                short8 a2h = *(const short8*)(sh2hi + aoff + kk * 32);
                short8 a2l = *(const short8*)(sh2lo + aoff + kk * 32);
                acc2a = __builtin_amdgcn_mfma_f32_16x16x32_bf16(a2h, bW3[kk], acc2a, 0, 0, 0);
                acc2b = __builtin_amdgcn_mfma_f32_16x16x32_bf16(a2l, bW3[kk], acc2b, 0, 0, 0);
            }
        }
        // D layout: col n=lane&15 (gate-row local), row m=(lane>>4)*4+r (batch)
#pragma unroll
        for (int r = 0; r < 4; ++r) {
            int m = (l >> 4) * 4 + r;
            gbuf1[(g * 16 + m) * 36 + hh * 16 + nloc] = acc1a[r] + acc1b[r];
            gbuf2[(g * 16 + m) * 36 + hh * 16 + nloc] = acc2a[r] + acc2b[r];
        }
        __syncthreads();

        u16 hi2 = 0;
        if (k < TT) {   // cell 1, t = k
            float xv = xs[k * 16 + cb];
            float g0 = gbuf1[(0 * 16 + cb) * 36 + ci] + xv * wihs[ci]      + b1s[ci];
            float g1 = gbuf1[(1 * 16 + cb) * 36 + ci] + xv * wihs[32 + ci] + b1s[32 + ci];
            float g2 = gbuf1[(2 * 16 + cb) * 36 + ci] + xv * wihs[64 + ci] + b1s[64 + ci];
            float g3 = gbuf1[(3 * 16 + cb) * 36 + ci] + xv * wihs[96 + ci] + b1s[96 + ci];
            float ii = sigf(g0), ff = sigf(g1), gg = tanhf_(g2), oo = sigf(g3);
            c1 = ff * c1 + ii * gg;
            float h = oo * tanhf_(c1);
            u16 hi = f2bf(h); u32 word = (u32)hi | ((u32)f2bf(h - bf2f(hi)) << 16);
            astore32(&Hb1[((wp * 256 + bg) << 8) + ig], word);
        }
        if (k > 0) {    // cell 2, t = k-1
            float g0 = gbuf2[(0 * 16 + cb) * 36 + ci] + b2s[ci];
            float g1 = gbuf2[(1 * 16 + cb) * 36 + ci] + b2s[32 + ci];
            float g2 = gbuf2[(2 * 16 + cb) * 36 + ci] + b2s[64 + ci];
            float g3 = gbuf2[(3 * 16 + cb) * 36 + ci] + b2s[96 + ci];
            float ii = sigf(g0), ff = sigf(g1), gg = tanhf_(g2), oo = sigf(g3);
            c2 = ff * c2 + ii * gg;
            float h = oo * tanhf_(c2);
            hi2 = f2bf(h); u32 word = (u32)hi2 | ((u32)f2bf(h - bf2f(hi2)) << 16);
            astore32(&Hb2[((wp * 256 + bg) << 8) + ig], word);
        }
        flag_post(flags, gb * 8 + hg, (u32)(k + 2));
        // HBM store for the attention pass — AFTER the post, off the critical path
        if (k > 0) H2out[(bg * TT + (k - 1)) * 256 + ig] = hi2;
    }
}

// ---- fused attention: per 64-row tile, S1=tanh(H2@Wa1^T+ba1) -> S2=S1@Wa2^T+ba2
//      -> softmax rows -> out = sum_n p*h2*Wo + bo. MFMA for both matmuls.
__global__ __launch_bounds__(256) void attn_fused(
    const u16*  __restrict__ Wa1b, const u16* __restrict__ Wa2b,
    const float* __restrict__ ba1, const float* __restrict__ ba2,
    const float* __restrict__ Wo,  const float* __restrict__ bo,
    const u16*  __restrict__ H2,   float* __restrict__ out)
{
    __shared__ __align__(16) u16 sA[64 * 264];
    __shared__ __align__(16) u16 sP[64 * 264];
    __shared__ float red[64 * 12];
    __shared__ float sb1[256], sb2[256], swo[256];

    const int tid = threadIdx.x;
    const int w = tid >> 6, l = tid & 63;
    const int c = l & 15, q = l >> 4;
    const int row0 = blockIdx.x * 64;

    {
        const int r = tid >> 2, qq = tid & 3;
        const uint4* src = (const uint4*)(H2 + (row0 + r) * 256 + qq * 64);
#pragma unroll
        for (int j = 0; j < 8; ++j) {
            uint4 v = src[j];
            *(uint4*)(sA + r * 264 + qq * 64 + j * 8) = v;
        }
    }
    if (tid < 256) { sb1[tid] = ba1[tid]; sb2[tid] = ba2[tid]; swo[tid] = Wo[tid]; }
    __syncthreads();

    f32x4 acc[4][4];
#pragma unroll
    for (int mi = 0; mi < 4; ++mi)
#pragma unroll
        for (int ni = 0; ni < 4; ++ni) acc[mi][ni] = (f32x4){0,0,0,0};

#pragma unroll
    for (int ni = 0; ni < 4; ++ni) {
        const int row = w * 64 + ni * 16 + c;
        const u16* wp = Wa1b + row * 256 + q * 8;
        short8 bW[8];
#pragma unroll
        for (int kk = 0; kk < 8; ++kk) bW[kk] = *(const short8*)(wp + kk * 32);
#pragma unroll
        for (int kk = 0; kk < 8; ++kk)
#pragma unroll
            for (int mi = 0; mi < 4; ++mi) {
                short8 a = *(const short8*)(sA + (mi * 16 + c) * 264 + q * 8 + kk * 32);
                acc[mi][ni] = __builtin_amdgcn_mfma_f32_16x16x32_bf16(a, bW[kk], acc[mi][ni], 0, 0, 0);
            }
    }
#pragma unroll
    for (int mi = 0; mi < 4; ++mi)
#pragma unroll
        for (int ni = 0; ni < 4; ++ni) {
            const int n = w * 64 + ni * 16 + c;
            const float bj = sb1[n];
#pragma unroll
            for (int r = 0; r < 4; ++r) {
                int m = mi * 16 + q * 4 + r;
                sP[m * 264 + n] = f2bf(tanhf(acc[mi][ni][r] + bj));
            }
        }
    __syncthreads();

#pragma unroll
    for (int mi = 0; mi < 4; ++mi)
#pragma unroll
        for (int ni = 0; ni < 4; ++ni) acc[mi][ni] = (f32x4){0,0,0,0};
#pragma unroll
    for (int ni = 0; ni < 4; ++ni) {
        const int row = w * 64 + ni * 16 + c;
        const u16* wp = Wa2b + row * 256 + q * 8;
        short8 bW[8];
#pragma unroll
        for (int kk = 0; kk < 8; ++kk) bW[kk] = *(const short8*)(wp + kk * 32);
#pragma unroll
        for (int kk = 0; kk < 8; ++kk)
#pragma unroll
            for (int mi = 0; mi < 4; ++mi) {
                short8 a = *(const short8*)(sP + (mi * 16 + c) * 264 + q * 8 + kk * 32);
                acc[mi][ni] = __builtin_amdgcn_mfma_f32_16x16x32_bf16(a, bW[kk], acc[mi][ni], 0, 0, 0);
            }
    }

    float mx[4][4];
#pragma unroll
    for (int mi = 0; mi < 4; ++mi)
#pragma unroll
        for (int r = 0; r < 4; ++r) mx[mi][r] = -1e30f;
#pragma unroll
    for (int mi = 0; mi < 4; ++mi)
#pragma unroll
        for (int ni = 0; ni < 4; ++ni) {
            const float bj = sb2[w * 64 + ni * 16 + c];
#pragma unroll
            for (int r = 0; r < 4; ++r) {
                float s = acc[mi][ni][r] + bj;
                acc[mi][ni][r] = s;
                mx[mi][r] = fmaxf(mx[mi][r], s);
            }
        }
#pragma unroll
    for (int off = 1; off < 16; off <<= 1)
#pragma unroll
        for (int mi = 0; mi < 4; ++mi)
#pragma unroll
            for (int r = 0; r < 4; ++r) mx[mi][r] = fmaxf(mx[mi][r], __shfl_xor(mx[mi][r], off));
    if (c == 0)
#pragma unroll
        for (int mi = 0; mi < 4; ++mi)
#pragma unroll
            for (int r = 0; r < 4; ++r) red[(mi * 16 + q * 4 + r) * 12 + w] = mx[mi][r];
    __syncthreads();
#pragma unroll
    for (int mi = 0; mi < 4; ++mi)
#pragma unroll
        for (int r = 0; r < 4; ++r) {
            const float* rp = red + (mi * 16 + q * 4 + r) * 12;
            mx[mi][r] = fmaxf(fmaxf(rp[0], rp[1]), fmaxf(rp[2], rp[3]));
        }
    float suml[4][4], sumw[4][4];
#pragma unroll
    for (int mi = 0; mi < 4; ++mi)
#pragma unroll
        for (int r = 0; r < 4; ++r) { suml[mi][r] = 0.f; sumw[mi][r] = 0.f; }
#pragma unroll
    for (int mi = 0; mi < 4; ++mi)
#pragma unroll
        for (int ni = 0; ni < 4; ++ni) {
            const int n = w * 64 + ni * 16 + c;
            const float wov = swo[n];
#pragma unroll
            for (int r = 0; r < 4; ++r) {
                int m = mi * 16 + q * 4 + r;
                float e = __expf(acc[mi][ni][r] - mx[mi][r]);
                suml[mi][r] += e;
                sumw[mi][r] += e * bf2f(sA[m * 264 + n]) * wov;
            }
        }
#pragma unroll
    for (int off = 1; off < 16; off <<= 1)
#pragma unroll
        for (int mi = 0; mi < 4; ++mi)
#pragma unroll
            for (int r = 0; r < 4; ++r) {
                suml[mi][r] += __shfl_xor(suml[mi][r], off);
                sumw[mi][r] += __shfl_xor(sumw[mi][r], off);
            }
    __syncthreads();
    if (c == 0)
#pragma unroll
        for (int mi = 0; mi < 4; ++mi)
#pragma unroll
            for (int r = 0; r < 4; ++r) {
                int m = mi * 16 + q * 4 + r;
                red[m * 12 + 4 + w] = suml[mi][r];
                red[m * 12 + 8 + w] = sumw[mi][r];
            }
    __syncthreads();
    if (tid < 64) {
        const float* rp = red + tid * 12;
        float lsum = rp[4] + rp[5] + rp[6] + rp[7];
        float wsum = rp[8] + rp[9] + rp[10] + rp[11];
        out[row0 + tid] = wsum / lsum + bo[0];
    }
}

extern "C" void kernel_launch(void* const* d_in, const int* in_sizes, int n_in,
                              void* d_out, int out_size, void* d_ws, size_t ws_size,
                              hipStream_t stream) {
    const float* x    = (const float*)d_in[0];
    const float* Wih1 = (const float*)d_in[1];
    const float* bih1 = (const float*)d_in[2];
    const float* Whh1 = (const float*)d_in[3];
    const float* bhh1 = (const float*)d_in[4];
    const float* Wih2 = (const float*)d_in[5];
    const float* bih2 = (const float*)d_in[6];
    const float* Whh2 = (const float*)d_in[7];
    const float* bhh2 = (const float*)d_in[8];
    const float* Wa1  = (const float*)d_in[9];
    const float* ba1  = (const float*)d_in[10];
    const float* Wa2  = (const float*)d_in[11];
    const float* ba2  = (const float*)d_in[12];
    const float* Wo   = (const float*)d_in[13];
    const float* bo   = (const float*)d_in[14];

    char* ws = (char*)d_ws;
    u16*   Wa1b  = (u16*)(ws + 0);                  // 128 KB
    u16*   Wa2b  = (u16*)(ws + 131072);             // 128 KB
    float* bias1 = (float*)(ws + 262144);           // 4 KB
    float* bias2 = (float*)(ws + 266240);           // 4 KB
    u32*   flags = (u32*)(ws + 270336);             // 16 KB (128 x 128B slots)
    u32*   Hb1   = (u32*)(ws + 524288);             // 512 KB [2][256][256] u32
    u32*   Hb2   = (u32*)(ws + 1048576);            // 512 KB
    u16*   H2    = (u16*)(ws + 2097152);            // 64 MB
    float* out   = (float*)d_out;

    (void)hipMemsetAsync(flags, 0, 16384, stream);
    bias_kernel<<<4, 256, 0, stream>>>(bih1, bhh1, bih2, bhh2, bias1, bias2);
    cvt_bf_kernel<<<256, 256, 0, stream>>>(Wa1, Wa1b, 65536);
    cvt_bf_kernel<<<256, 256, 0, stream>>>(Wa2, Wa2b, 65536);

    lstm_persist<<<128, 512, 0, stream>>>(x, Wih1, bias1, bias2,
                                          Whh1, Wih2, Whh2, Hb1, Hb2, H2, flags);
    attn_fused<<<2048, 256, 0, stream>>>(Wa1b, Wa2b, ba1, ba2, Wo, bo, H2, out);
}